// Round 6
// baseline (111.874 us; speedup 1.0000x reference)
//
#include <hip/hip_runtime.h>
#include <hip/hip_cooperative_groups.h>
#include <math.h>

#define Bb 64
#define Ss 512
#define Hh 768
#define Ll 9
#define CCH 16      // chunks per batch
#define TCH 32      // steps per chunk
#define NROWS (Bb * Ss)

namespace cg = cooperative_groups;

// ---------------- emissions phase: wave-per-row GEMV ----------------
// lane i owns k = {je>>2 * 256 + i*4 + (je&3)}; W fragment in registers.
__device__ __forceinline__ void emis_rows(
    const float* __restrict__ hs, const float* __restrict__ W,
    const float* __restrict__ bvec, const float* __restrict__ cw,
    float* __restrict__ emis, int wave, int nwav)
{
    const int lane = threadIdx.x & 63;
    float w[12][Ll];
#pragma unroll
    for (int je = 0; je < 12; ++je) {
        const int k = (je >> 2) * 256 + lane * 4 + (je & 3);
#pragma unroll
        for (int l = 0; l < Ll; ++l) w[je][l] = W[k * Ll + l];
    }
    const int sel = lane & 15;
    const int ml = (lane < Ll) ? lane : 0;
    const float myb = bvec[ml], myc = cw[ml];

    for (int row = wave; row < NROWS; row += nwav) {
        const float4* rp = (const float4*)(hs + (size_t)row * Hh);
        const float4 x0 = rp[lane], x1 = rp[64 + lane], x2 = rp[128 + lane];
        float acc[Ll];
#pragma unroll
        for (int l = 0; l < Ll; ++l) acc[l] = 0.f;
        const float xs[12] = {x0.x, x0.y, x0.z, x0.w,
                              x1.x, x1.y, x1.z, x1.w,
                              x2.x, x2.y, x2.z, x2.w};
#pragma unroll
        for (int je = 0; je < 12; ++je)
#pragma unroll
            for (int l = 0; l < Ll; ++l)
                acc[l] = fmaf(xs[je], w[je][l], acc[l]);
        // reduce: xor 1,2,4,8 on all 9 -> 16-lane-group sums
#pragma unroll
        for (int off = 1; off <= 8; off <<= 1)
#pragma unroll
            for (int l = 0; l < Ll; ++l)
                acc[l] += __shfl_xor(acc[l], off);
        // lane picks value (lane&15), then xor 16,32 completes the 64-lane sum
        float v = acc[0];
#pragma unroll
        for (int l = 1; l < Ll; ++l) v = (sel == l) ? acc[l] : v;
        v += __shfl_xor(v, 16);
        v += __shfl_xor(v, 32);
        if (lane < Ll) emis[(size_t)row * Ll + lane] = (v + myb) * myc;
    }
}

// ---------------- CRF phase for one batch (256 threads) ----------------
__device__ __forceinline__ void crf_batch(
    int b, const float* __restrict__ emis, const int* __restrict__ labels,
    const int* __restrict__ attn, const float* __restrict__ trans,
    const float* __restrict__ startt, const float* __restrict__ endt,
    float* __restrict__ out)
{
    __shared__ int   mkt_s[Ss];          // tag | (mk<<4)
    __shared__ float emis_s[Ss * Ll];    // 18 KB
    __shared__ float trans_s[Ll * Ll];
    __shared__ float et_s[Ll * Ll];      // exp(trans)
    __shared__ float erow_s[CCH * Ll * Ll];
    __shared__ float rowmax_s[CCH * Ll];
    __shared__ float num_s;

    const int tid = threadIdx.x;

    // ---- stage ----
#pragma unroll
    for (int it = 0; it < 2; ++it) {
        const int t = tid + it * 256;
        const int lab = labels[b * Ss + t];
        const int att = attn[b * Ss + t];
        const int tag = (lab == -100) ? 0 : lab;
        const int mk  = ((lab != -100) && (att == 1)) ? 1 : 0;
        mkt_s[t] = tag | (mk << 4);
    }
    {
        const float4* src = (const float4*)(emis + (size_t)b * Ss * Ll);
        float4* dst = (float4*)emis_s;
        for (int i = tid; i < (Ss * Ll) / 4; i += 256) dst[i] = src[i];
    }
    if (tid < Ll * Ll) {
        const float tv = trans[tid];
        trans_s[tid] = tv;
        et_s[tid] = __expf(tv);
    }
    __syncthreads();

    // ---- chunk workers: tid < 144; row i of chunk c's 9x9 transfer matrix ----
    if (tid < CCH * Ll) {
        const int i = tid % Ll;
        const int c = tid / Ll;
        float et[Ll][Ll];
#pragma unroll
        for (int l = 0; l < Ll; ++l)
#pragma unroll
            for (int k = 0; k < Ll; ++k) et[l][k] = et_s[l * Ll + k];
        float vv[Ll];
#pragma unroll
        for (int l = 0; l < Ll; ++l) vv[l] = (l == i) ? 0.f : -1e30f;
        for (int s = (c == 0 ? 1 : 0); s < TCH; ++s) {
            const int t = c * TCH + s;
            const int mv = mkt_s[t];
            if (mv >> 4) {
                const float* e = emis_s + t * Ll;
                float m = vv[0];
#pragma unroll
                for (int l = 1; l < Ll; ++l) m = fmaxf(m, vv[l]);
                float p[Ll];
#pragma unroll
                for (int l = 0; l < Ll; ++l) p[l] = __expf(vv[l] - m);
                float nv[Ll];
#pragma unroll
                for (int k = 0; k < Ll; ++k) {
                    float sacc = 0.f;
#pragma unroll
                    for (int l = 0; l < Ll; ++l) sacc = fmaf(p[l], et[l][k], sacc);
                    nv[k] = m + __logf(sacc) + e[k];
                }
#pragma unroll
                for (int l = 0; l < Ll; ++l) vv[l] = nv[l];
            }
        }
        float m = vv[0];
#pragma unroll
        for (int l = 1; l < Ll; ++l) m = fmaxf(m, vv[l]);
        rowmax_s[c * Ll + i] = m;
#pragma unroll
        for (int l = 0; l < Ll; ++l)
            erow_s[(c * Ll + i) * Ll + l] = __expf(vv[l] - m);
    }

    // ---- numerator: wave 3 (tid 192..255) ----
    if (tid >= 192) {
        const int lane = tid - 192;
        float psum = 0.f;
        int pcnt = 0;
        for (int t = lane; t < Ss; t += 64) {
            const int mv  = mkt_s[t];
            const int tag = mv & 15;
            const bool mk = (mv >> 4) || (t == 0);
            if (t >= 1 && (mv >> 4)) {
                const int tagp = mkt_s[t - 1] & 15;
                psum += trans_s[tagp * Ll + tag] + emis_s[t * Ll + tag];
            }
            pcnt += mk ? 1 : 0;
        }
#pragma unroll
        for (int off = 32; off; off >>= 1) {
            psum += __shfl_xor(psum, off);
            pcnt += __shfl_xor(pcnt, off);
        }
        if (lane == 0) {
            const int tag0 = mkt_s[0] & 15;
            const int tagL = mkt_s[pcnt - 1] & 15;
            num_s = startt[tag0] + emis_s[tag0] + psum + endt[tagL];
        }
    }
    __syncthreads();

    // ---- compose: lanes 0..8 of wave 0 (lane k owns column k) ----
    if (tid < Ll) {
        const int lane = tid;
        float sc[Ll];
#pragma unroll
        for (int l = 0; l < Ll; ++l) sc[l] = startt[l] + emis_s[l];
        for (int c = 0; c < CCH; ++c) {
            float u[Ll];
#pragma unroll
            for (int l = 0; l < Ll; ++l) u[l] = sc[l] + rowmax_s[c * Ll + l];
            float M = u[0];
#pragma unroll
            for (int l = 1; l < Ll; ++l) M = fmaxf(M, u[l]);
            float sacc = 0.f;
#pragma unroll
            for (int l = 0; l < Ll; ++l)
                sacc = fmaf(__expf(u[l] - M), erow_s[(c * Ll + l) * Ll + lane], sacc);
            const float ns = M + __logf(sacc);
#pragma unroll
            for (int l = 0; l < Ll; ++l) sc[l] = __shfl(ns, l);
        }
        // final logsumexp with end transitions (all-register, replicated)
        float M2 = sc[0] + endt[0];
#pragma unroll
        for (int l = 1; l < Ll; ++l) M2 = fmaxf(M2, sc[l] + endt[l]);
        float s2 = 0.f;
#pragma unroll
        for (int l = 0; l < Ll; ++l) s2 += __expf(sc[l] + endt[l] - M2);
        if (lane == 0) {
            const float logz = M2 + __logf(s2);
            atomicAdd(out, -(num_s - logz) * (1.f / Bb));
        }
    }
}

// ---------------- single cooperative kernel ----------------
__global__ __launch_bounds__(256, 2) void k_fused(
    const float* __restrict__ hs, const float* __restrict__ W,
    const float* __restrict__ bvec, const float* __restrict__ cw,
    const float* __restrict__ startt, const float* __restrict__ endt,
    const float* __restrict__ trans, const int* __restrict__ labels,
    const int* __restrict__ attn, float* __restrict__ emis,
    float* __restrict__ out)
{
    const int wave = blockIdx.x * 4 + (threadIdx.x >> 6);
    emis_rows(hs, W, bvec, cw, emis, wave, gridDim.x * 4);
    if (blockIdx.x == 0 && threadIdx.x == 0) out[0] = 0.f;
    cg::this_grid().sync();
    if (blockIdx.x < Bb)
        crf_batch(blockIdx.x, emis, labels, attn, trans, startt, endt, out);
}

// ---------------- fallback (non-cooperative) path ----------------
__global__ __launch_bounds__(256) void k_emis(
    const float* __restrict__ hs, const float* __restrict__ W,
    const float* __restrict__ bvec, const float* __restrict__ cw,
    float* __restrict__ emis, float* __restrict__ out)
{
    if (blockIdx.x == 0 && threadIdx.x == 0) out[0] = 0.f;
    const int wave = blockIdx.x * 4 + (threadIdx.x >> 6);
    emis_rows(hs, W, bvec, cw, emis, wave, gridDim.x * 4);
}

__global__ __launch_bounds__(256) void k_crf(
    const float* __restrict__ emis, const int* __restrict__ labels,
    const int* __restrict__ attn, const float* __restrict__ trans,
    const float* __restrict__ startt, const float* __restrict__ endt,
    float* __restrict__ out)
{
    crf_batch(blockIdx.x, emis, labels, attn, trans, startt, endt, out);
}

extern "C" void kernel_launch(void* const* d_in, const int* in_sizes, int n_in,
                              void* d_out, int out_size, void* d_ws, size_t ws_size,
                              hipStream_t stream)
{
    const float* hs     = (const float*)d_in[0];
    const float* W      = (const float*)d_in[1];
    const float* bvec   = (const float*)d_in[2];
    const float* cw     = (const float*)d_in[3];
    const float* startt = (const float*)d_in[4];
    const float* endt   = (const float*)d_in[5];
    const float* trans  = (const float*)d_in[6];
    const int*   labels = (const int*)d_in[7];
    const int*   attn   = (const int*)d_in[8];
    float* out  = (float*)d_out;
    float* emis = (float*)d_ws;   // 64*512*9 floats

    // host-side capability check (legal under graph capture: no stream ops)
    int coop = 0;
    {
        int dev = 0;
        hipGetDevice(&dev);
        hipDeviceGetAttribute(&coop, hipDeviceAttributeCooperativeLaunch, dev);
    }

    hipError_t err = hipErrorNotSupported;
    if (coop) {
        void* args[] = {(void*)&hs, (void*)&W, (void*)&bvec, (void*)&cw,
                        (void*)&startt, (void*)&endt, (void*)&trans,
                        (void*)&labels, (void*)&attn, (void*)&emis, (void*)&out};
        err = hipLaunchCooperativeKernel((const void*)k_fused,
                                         dim3(512), dim3(256),
                                         args, 0u, stream);
    }
    if (err != hipSuccess) {
        // fallback: 2 plain dispatches (out zeroed inside k_emis)
        hipLaunchKernelGGL(k_emis, dim3(1024), dim3(256), 0, stream,
                           hs, W, bvec, cw, emis, out);
        hipLaunchKernelGGL(k_crf, dim3(Bb), dim3(256), 0, stream,
                           emis, labels, attn, trans, startt, endt, out);
    }
}